// Round 4
// baseline (5014.151 us; speedup 1.0000x reference)
//
#include <hip/hip_runtime.h>

// ---------------------------------------------------------------------------
// 2-layer Elman RNN LM forward on MI355X — mega-kernel edition.
// Pre: Wih0 transpose, embed, U0 GEMM.
// k_mega (512 WGs x 256 thr, all co-resident at 2 WGs/CU):
//   WG 0-15  : rec layer0 (Whh0 in VGPRs, fence-free atomic h exchange)
//   WG 16-47 : rec layer1 (wave pairs: A=Wih1, B=Whh1, LDS partial combine)
//   WG 48-511: workers — transpose Wfc->WfcT, then work-steal logits-GEMM
//              tiles gated on L1 progress flags; emit logits + lse partials.
// Post: partial-combine -> rowloss -> mean loss.
// Coherence: h/flags via agent-scope relaxed atomics (LLC), ack-ordered
// publishes (vmcnt(0) before flag) — NO acquire fences anywhere in loops.
// FEATS/WfcT safe for cached reads: lines are never read before final.
// ---------------------------------------------------------------------------

#define H_DIM 1024
#define B_SZ 8
#define T_SZ 512
#define V_SZ 50257
#define V_PAD 50304
#define NWORK 464
#define NTILES 12576   // 4 phases x 393 nblk x 8 b

typedef __attribute__((ext_vector_type(8))) short bf16x8;
typedef __attribute__((ext_vector_type(4))) float f32x4;

__device__ __forceinline__ unsigned short f2bf(float f) {
  unsigned int u = __float_as_uint(f);
  u += 0x7fffu + ((u >> 16) & 1u);
  return (unsigned short)(u >> 16);
}
__device__ __forceinline__ float bf2f(unsigned short h) {
  return __uint_as_float(((unsigned int)h) << 16);
}
__device__ __forceinline__ float ftanh(float x) {
  float e = __expf(2.f * x);
  return 1.f - 2.f / (e + 1.f);
}
__device__ __forceinline__ int aload32(const int* p) {
  return __hip_atomic_load(p, __ATOMIC_RELAXED, __HIP_MEMORY_SCOPE_AGENT);
}
__device__ __forceinline__ void astore32(unsigned int* p, unsigned int v) {
  __hip_atomic_store(p, v, __ATOMIC_RELAXED, __HIP_MEMORY_SCOPE_AGENT);
}
__device__ __forceinline__ void astore32i(int* p, int v) {
  __hip_atomic_store(p, v, __ATOMIC_RELAXED, __HIP_MEMORY_SCOPE_AGENT);
}
__device__ __forceinline__ unsigned long long aload64(const void* p) {
  return __hip_atomic_load((const unsigned long long*)p, __ATOMIC_RELAXED,
                           __HIP_MEMORY_SCOPE_AGENT);
}
__device__ __forceinline__ void gload_lds16(const void* g, void* l) {
  __builtin_amdgcn_global_load_lds(
      (const __attribute__((address_space(1))) void*)g,
      (__attribute__((address_space(3))) void*)l, 16, 0, 0);
}

// ---------------- transpose f32 [K][N] -> bf16 [Npad][K] (pre, Wih0) -------
__global__ __launch_bounds__(256) void k_transpose(
    const float* __restrict__ in, unsigned short* __restrict__ out,
    int K, int N, int Npad)
{
  __shared__ float tile[32][33];
  const int n0 = blockIdx.x * 32, k0 = blockIdx.y * 32;
  const int tx = threadIdx.x, ty = threadIdx.y;
#pragma unroll
  for (int jj = 0; jj < 4; ++jj) {
    int k = k0 + ty + jj * 8, n = n0 + tx;
    tile[ty + jj * 8][tx] = (n < N) ? in[(size_t)k * N + n] : 0.f;
  }
  __syncthreads();
#pragma unroll
  for (int jj = 0; jj < 4; ++jj) {
    int n = n0 + ty + jj * 8, k = k0 + tx;
    if (n < Npad) out[(size_t)n * K + k] = f2bf((n < N) ? tile[tx][ty + jj * 8] : 0.f);
  }
}

// ---------------- embedding gather -> time-major bf16 [T*B][512] ------------
__global__ __launch_bounds__(128) void k_embed(
    const int* __restrict__ x, const float* __restrict__ E,
    unsigned short* __restrict__ xe)
{
  const int r = blockIdx.x;
  const int t = r >> 3, b = r & 7;
  const int tok = x[b * T_SZ + t];
  const float4 v = ((const float4*)(E + (size_t)tok * 512))[threadIdx.x];
  ushort4 o;
  o.x = f2bf(v.x); o.y = f2bf(v.y); o.z = f2bf(v.z); o.w = f2bf(v.w);
  *((ushort4*)(xe + (size_t)r * 512) + threadIdx.x) = o;
}

// ---------------- standalone bf16 MFMA GEMM (U0 only) -----------------------
template <bool BF16_OUT, bool BIAS>
__global__ __launch_bounds__(256) void k_gemm(
    const unsigned short* __restrict__ A, const unsigned short* __restrict__ Bt,
    void* __restrict__ Cout, const float* __restrict__ bias,
    int Nvalid, int K, int lda, int ldb, int ldc)
{
  __shared__ unsigned short As[8192];
  __shared__ unsigned short Bs[8192];
  const int tid = threadIdx.x;
  const int n0 = blockIdx.x * 128;
  const int m0 = blockIdx.y * 128;
  const int lane = tid & 63;
  const int wv = tid >> 6;
  const int wm = wv >> 1, wn = wv & 1;
  const int ln = lane & 15, cc = lane >> 4;
  f32x4 acc[4][4] = {};
  const int rr = tid >> 3;
  const int cb = (tid & 7) << 4;

  for (int kb = 0; kb < K; kb += 64) {
    __syncthreads();
#pragma unroll
    for (int is = 0; is < 4; ++is) {
      int r = is * 32 + rr;
      int sb = cb ^ ((r & 7) << 4);
      gload_lds16((const char*)(A + (size_t)(m0 + r) * lda + kb) + sb,
                  &As[(is * 32 + 8 * wv) * 64]);
    }
#pragma unroll
    for (int is = 0; is < 4; ++is) {
      int r = is * 32 + rr;
      int sb = cb ^ ((r & 7) << 4);
      gload_lds16((const char*)(Bt + (size_t)(n0 + r) * ldb + kb) + sb,
                  &Bs[(is * 32 + 8 * wv) * 64]);
    }
    __syncthreads();
#pragma unroll
    for (int kk = 0; kk < 2; ++kk) {
      bf16x8 af[4], bfr[4];
      const int kslot = kk * 64 + cc * 16;
#pragma unroll
      for (int mi = 0; mi < 4; ++mi) {
        int ra = wm * 64 + mi * 16 + ln;
        af[mi] = *(const bf16x8*)((const char*)As + ra * 128 + (kslot ^ ((ra & 7) << 4)));
      }
#pragma unroll
      for (int ni = 0; ni < 4; ++ni) {
        int rb = wn * 64 + ni * 16 + ln;
        bfr[ni] = *(const bf16x8*)((const char*)Bs + rb * 128 + (kslot ^ ((rb & 7) << 4)));
      }
#pragma unroll
      for (int mi = 0; mi < 4; ++mi)
#pragma unroll
        for (int ni = 0; ni < 4; ++ni)
          acc[mi][ni] = __builtin_amdgcn_mfma_f32_16x16x32_bf16(af[mi], bfr[ni], acc[mi][ni], 0, 0, 0);
    }
  }
#pragma unroll
  for (int ni = 0; ni < 4; ++ni) {
    const int col = n0 + wn * 64 + ni * 16 + ln;
    const bool cok = col < Nvalid;
    float bv = 0.f;
    if (BIAS && cok) bv = bias[col];
#pragma unroll
    for (int mi = 0; mi < 4; ++mi) {
#pragma unroll
      for (int i = 0; i < 4; ++i) {
        if (cok) {
          const int rowg = m0 + wm * 64 + mi * 16 + cc * 4 + i;
          if (BF16_OUT)
            ((unsigned short*)Cout)[(size_t)rowg * ldc + col] = f2bf(acc[mi][ni][i]);
          else
            ((float*)Cout)[(size_t)rowg * ldc + col] = acc[mi][ni][i] + bv;
        }
      }
    }
  }
}

// ---------------- rec layer 0 ------------------------------------------------
__device__ void rec0_body(const unsigned short* U0, const float* Whh0,
    unsigned int* h0buf, int* flags, char* smem, int wgl)
{
  __builtin_amdgcn_s_setprio(2);
  const int tid = threadIdx.x, lane = tid & 63, wv = tid >> 6;
  const int ln = lane & 15, cc = lane >> 4, r = ln & 7;
  const int n0 = wgl * 64 + wv * 16, col = n0 + ln, gw = wgl * 4 + wv;
  char* hs = smem;  // 16 KB shared h0 stage

  bf16x8 bw[32];
#pragma unroll
  for (int kc = 0; kc < 32; ++kc) {
    const float* wp = Whh0 + (size_t)(kc * 32 + cc * 8) * H_DIM + col;
    bf16x8 v;
#pragma unroll
    for (int q = 0; q < 8; ++q) v[q] = (short)f2bf(wp[(size_t)q * H_DIM]);
    bw[kc] = v;
  }

#pragma unroll 1
  for (int t = 0; t < T_SZ; ++t) {
    unsigned short uva[4] = {0, 0, 0, 0};
    if (cc < 2) {
#pragma unroll
      for (int i = 0; i < 4; ++i)
        uva[i] = U0[(size_t)(t * B_SZ + cc * 4 + i) * H_DIM + col];
    }
    {
      const int* fa = flags + lane * 32;        // L0 wave flags
      const int* fb = flags + (64 + lane) * 32; // L1 tile flags
      for (;;) {
        int va = aload32(fa), vb = aload32(fb);
        if (__all(va >= t && vb >= t - 1)) break;
        __builtin_amdgcn_s_sleep(1);
      }
    }
    __syncthreads();                            // prev-tick LDS reads done
    const char* hg = (const char*)(h0buf + (t & 1) * 4096);
#pragma unroll
    for (int q = 0; q < 8; ++q) {               // wave stages rows 2wv,2wv+1
      int idx = q * 512 + lane * 8;
      int row = wv * 2 + (idx >> 11), b = idx & 2047;
      unsigned long long v = aload64(hg + (size_t)row * 2048 + b);
      *(unsigned long long*)(hs + row * 2048 + (b ^ ((row & 7) << 4))) = v;
    }
    __syncthreads();
    f32x4 ac0 = {}, ac1 = {};
#pragma unroll
    for (int kc = 0; kc < 32; kc += 2) {
      bf16x8 a0 = *(const bf16x8*)(hs + r * 2048 + ((kc * 64 + cc * 16) ^ (r << 4)));
      bf16x8 a1 = *(const bf16x8*)(hs + r * 2048 + (((kc + 1) * 64 + cc * 16) ^ (r << 4)));
      ac0 = __builtin_amdgcn_mfma_f32_16x16x32_bf16(a0, bw[kc], ac0, 0, 0, 0);
      ac1 = __builtin_amdgcn_mfma_f32_16x16x32_bf16(a1, bw[kc + 1], ac1, 0, 0, 0);
    }
    float hv[4] = {0.f, 0.f, 0.f, 0.f};
    if (cc < 2) {
#pragma unroll
      for (int i = 0; i < 4; ++i) hv[i] = ftanh(ac0[i] + ac1[i] + bf2f(uva[i]));
    }
    unsigned int wpk[4];
#pragma unroll
    for (int i = 0; i < 4; ++i) {
      float pv = __shfl_xor(hv[i], 1);
      wpk[i] = (unsigned)f2bf(hv[i]) | ((unsigned)f2bf(pv) << 16);
    }
    unsigned int* hn = h0buf + ((t + 1) & 1) * 4096;
    if (cc < 2 && !(ln & 1)) {
#pragma unroll
      for (int i = 0; i < 4; ++i)
        astore32(hn + (cc * 4 + i) * 512 + (col >> 1), wpk[i]);
    }
    asm volatile("s_waitcnt vmcnt(0)" ::: "memory");
    if (lane == 0) astore32i(flags + gw * 32, t + 1);
  }
}

// ---------------- rec layer 1 (wave pairs A=Wih1 / B=Whh1) ------------------
__device__ void rec1_body(const float* Wih1, const float* Whh1,
    unsigned short* feats, unsigned int* h0buf, unsigned int* h1buf,
    int* flags, char* smem, int wgl1)
{
  __builtin_amdgcn_s_setprio(2);
  const int tid = threadIdx.x, lane = tid & 63, wv = tid >> 6;
  const int ln = lane & 15, cc = lane >> 4, r = ln & 7;
  const int tix = wv >> 1, isB = wv & 1;
  const int tau = wgl1 * 2 + tix, n0 = tau * 16, col = n0 + ln;
  char* hs = smem;                       // [0,16K)=h0  [16K,32K)=h1
  float* part = (float*)(smem + 32768);  // 2 tiles x 1 KB

  const float* W = isB ? Whh1 : Wih1;
  bf16x8 bw[32];
#pragma unroll
  for (int kc = 0; kc < 32; ++kc) {
    const float* wp = W + (size_t)(kc * 32 + cc * 8) * H_DIM + col;
    bf16x8 v;
#pragma unroll
    for (int q = 0; q < 8; ++q) v[q] = (short)f2bf(wp[(size_t)q * H_DIM]);
    bw[kc] = v;
  }

#pragma unroll 1
  for (int t = 0; t < T_SZ; ++t) {
    {
      const int* fa = flags + lane * 32;
      const int* fb = flags + (64 + lane) * 32;
      for (;;) {
        int va = aload32(fa), vb = aload32(fb);
        if (__all(va >= t + 1 && vb >= t)) break;
        __builtin_amdgcn_s_sleep(1);
      }
    }
    __syncthreads();
    const char* hg0 = (const char*)(h0buf + ((t + 1) & 1) * 4096);
    const char* hg1 = (const char*)(h1buf + (t & 1) * 4096);
#pragma unroll
    for (int q = 0; q < 16; ++q) {       // wave stages rows 4wv..4wv+3 of 16
      int idx = q * 512 + lane * 8;
      int grow = wv * 4 + (idx >> 11), b = idx & 2047;
      const char* src = (grow < 8) ? hg0 + (size_t)grow * 2048 + b
                                   : hg1 + (size_t)(grow - 8) * 2048 + b;
      unsigned long long v = aload64(src);
      *(unsigned long long*)(hs + grow * 2048 + (b ^ ((grow & 7) << 4))) = v;
    }
    __syncthreads();
    const char* base = hs + isB * 16384;
    f32x4 ac0 = {}, ac1 = {};
#pragma unroll
    for (int kc = 0; kc < 32; kc += 2) {
      bf16x8 a0 = *(const bf16x8*)(base + r * 2048 + ((kc * 64 + cc * 16) ^ (r << 4)));
      bf16x8 a1 = *(const bf16x8*)(base + r * 2048 + (((kc + 1) * 64 + cc * 16) ^ (r << 4)));
      ac0 = __builtin_amdgcn_mfma_f32_16x16x32_bf16(a0, bw[kc], ac0, 0, 0, 0);
      ac1 = __builtin_amdgcn_mfma_f32_16x16x32_bf16(a1, bw[kc + 1], ac1, 0, 0, 0);
    }
    if (!isB) *(f32x4*)(part + tix * 256 + lane * 4) = ac0 + ac1;
    __syncthreads();
    if (isB) {
      f32x4 pa = *(const f32x4*)(part + tix * 256 + lane * 4);
      float hv[4] = {0.f, 0.f, 0.f, 0.f};
      if (cc < 2) {
#pragma unroll
        for (int i = 0; i < 4; ++i) hv[i] = ftanh(ac0[i] + ac1[i] + pa[i]);
      }
      unsigned int wpk[4];
#pragma unroll
      for (int i = 0; i < 4; ++i) {
        float pv = __shfl_xor(hv[i], 1);
        wpk[i] = (unsigned)f2bf(hv[i]) | ((unsigned)f2bf(pv) << 16);
      }
      unsigned int* hn = h1buf + ((t + 1) & 1) * 4096;
      const bool wr = (cc < 2) && !(ln & 1);
      if (wr) {
#pragma unroll
        for (int i = 0; i < 4; ++i)
          astore32(hn + (cc * 4 + i) * 512 + (col >> 1), wpk[i]);
      }
      asm volatile("s_waitcnt vmcnt(0)" ::: "memory");
      if (lane == 0) astore32i(flags + (64 + tau) * 32, t + 1);
      if (wr) {                           // FEATS drains under next poll
#pragma unroll
        for (int i = 0; i < 4; ++i)
          astore32((unsigned int*)feats +
                   (((size_t)(cc * 4 + i) * 524288 + (size_t)t * 1024 + col) >> 1),
                   wpk[i]);
      }
    }
  }
  asm volatile("s_waitcnt vmcnt(0)" ::: "memory");
  if (isB && lane == 0) astore32i(flags + (64 + tau) * 32, T_SZ + 1);
}

// ---------------- worker: gated logits-GEMM tile + lse partials -------------
__device__ void gemm_tile(const unsigned short* A, const unsigned short* Bt,
    float* C, const float* bias, float2* PARTg, char* smem,
    int m0, int n0, int nb)
{
  unsigned short* As = (unsigned short*)smem;
  unsigned short* Bs = (unsigned short*)(smem + 16384);
  float2* lpart = (float2*)(smem + 32768);
  const int tid = threadIdx.x;
  const int lane = tid & 63;
  const int wv = tid >> 6;
  const int wm = wv >> 1, wn = wv & 1;
  const int ln = lane & 15, cc = lane >> 4;
  f32x4 acc[4][4] = {};
  const int rr = tid >> 3;
  const int cb = (tid & 7) << 4;

  for (int kb = 0; kb < H_DIM; kb += 64) {
    __syncthreads();
#pragma unroll
    for (int is = 0; is < 4; ++is) {
      int r = is * 32 + rr;
      int sb = cb ^ ((r & 7) << 4);
      gload_lds16((const char*)(A + (size_t)(m0 + r) * H_DIM + kb) + sb,
                  &As[(is * 32 + 8 * wv) * 64]);
    }
#pragma unroll
    for (int is = 0; is < 4; ++is) {
      int r = is * 32 + rr;
      int sb = cb ^ ((r & 7) << 4);
      gload_lds16((const char*)(Bt + (size_t)(n0 + r) * H_DIM + kb) + sb,
                  &Bs[(is * 32 + 8 * wv) * 64]);
    }
    __syncthreads();
#pragma unroll
    for (int kk = 0; kk < 2; ++kk) {
      bf16x8 af[4], bfr[4];
      const int kslot = kk * 64 + cc * 16;
#pragma unroll
      for (int mi = 0; mi < 4; ++mi) {
        int ra = wm * 64 + mi * 16 + ln;
        af[mi] = *(const bf16x8*)((const char*)As + ra * 128 + (kslot ^ ((ra & 7) << 4)));
      }
#pragma unroll
      for (int ni = 0; ni < 4; ++ni) {
        int rb = wn * 64 + ni * 16 + ln;
        bfr[ni] = *(const bf16x8*)((const char*)Bs + rb * 128 + (kslot ^ ((rb & 7) << 4)));
      }
#pragma unroll
      for (int mi = 0; mi < 4; ++mi)
#pragma unroll
        for (int ni = 0; ni < 4; ++ni)
          acc[mi][ni] = __builtin_amdgcn_mfma_f32_16x16x32_bf16(af[mi], bfr[ni], acc[mi][ni], 0, 0, 0);
    }
  }
  // epilogue: logits store + per-row (max, sumexp) partials over this tile
  float bvn[4]; int ckn[4];
#pragma unroll
  for (int ni = 0; ni < 4; ++ni) {
    int col = n0 + wn * 64 + ni * 16 + ln;
    ckn[ni] = col < V_SZ;
    bvn[ni] = ckn[ni] ? bias[col] : 0.f;
  }
  float fm[16], fs[16];
#pragma unroll
  for (int mi = 0; mi < 4; ++mi) {
#pragma unroll
    for (int i = 0; i < 4; ++i) {
      float v[4];
#pragma unroll
      for (int ni = 0; ni < 4; ++ni) {
        float tv = acc[mi][ni][i] + bvn[ni];
        v[ni] = ckn[ni] ? tv : -1e30f;
        if (ckn[ni]) {
          int col = n0 + wn * 64 + ni * 16 + ln;
          C[(size_t)(m0 + wm * 64 + mi * 16 + cc * 4 + i) * V_SZ + col] = tv;
        }
      }
      float mx = fmaxf(fmaxf(v[0], v[1]), fmaxf(v[2], v[3]));
#pragma unroll
      for (int m = 1; m < 16; m <<= 1) mx = fmaxf(mx, __shfl_xor(mx, m));
      float se = __expf(v[0] - mx) + __expf(v[1] - mx) +
                 __expf(v[2] - mx) + __expf(v[3] - mx);
#pragma unroll
      for (int m = 1; m < 16; m <<= 1) se += __shfl_xor(se, m);
      fm[mi * 4 + i] = mx; fs[mi * 4 + i] = se;
    }
  }
  if (wn == 0 && ln == 0) {
#pragma unroll
    for (int mi = 0; mi < 4; ++mi)
#pragma unroll
      for (int i = 0; i < 4; ++i) {
        int rl = wm * 64 + mi * 16 + cc * 4 + i;
        lpart[rl] = make_float2(fm[mi * 4 + i], fs[mi * 4 + i]);
      }
  }
  __syncthreads();
  if (wn == 1 && ln == 0) {
#pragma unroll
    for (int mi = 0; mi < 4; ++mi)
#pragma unroll
      for (int i = 0; i < 4; ++i) {
        int rl = wm * 64 + mi * 16 + cc * 4 + i;
        float2 o = lpart[rl];
        float mx = fm[mi * 4 + i], se = fs[mi * 4 + i];
        float nm = fmaxf(mx, o.x);
        float S = se * __expf(mx - nm) + o.y * __expf(o.x - nm);
        PARTg[(size_t)(m0 + rl) * 393 + nb] = make_float2(nm, S);
      }
  }
}

__device__ void worker_body(const float* Wfc, unsigned short* WfcT,
    const unsigned short* FEATS, const float* bias, float* C, float2* PARTg,
    int* flags, int* TDONE, int* TILE, char* smem, int wid)
{
  const int tid = threadIdx.x;
  // phase 1: transpose Wfc f32 [1024][50257] -> WfcT bf16 [50304][1024]
  {
    float* tt = (float*)smem;  // [32][33]
    const int tx = tid & 31, ty = tid >> 5;
    for (int tile = wid; tile < 1572 * 32; tile += NWORK) {
      int n0 = (tile % 1572) * 32, k0 = (tile / 1572) * 32;
      __syncthreads();
#pragma unroll
      for (int jj = 0; jj < 4; ++jj) {
        int k = k0 + ty + jj * 8, n = n0 + tx;
        tt[(ty + jj * 8) * 33 + tx] = (n < V_SZ) ? Wfc[(size_t)k * V_SZ + n] : 0.f;
      }
      __syncthreads();
#pragma unroll
      for (int jj = 0; jj < 4; ++jj) {
        int n = n0 + ty + jj * 8, k = k0 + tx;
        float v = (n < V_SZ) ? tt[tx * 33 + ty + jj * 8] : 0.f;
        WfcT[(size_t)n * H_DIM + k] = f2bf(v);
      }
    }
    asm volatile("s_waitcnt vmcnt(0)" ::: "memory");
    __syncthreads();
    if (tid == 0)
      __hip_atomic_fetch_add(TDONE, 1, __ATOMIC_RELEASE, __HIP_MEMORY_SCOPE_AGENT);
    while (aload32(TDONE) < NWORK) __builtin_amdgcn_s_sleep(8);
    __syncthreads();
  }
  // phase 2: gated tile work-stealing
  int* sBC = (int*)(smem + 34560);
  for (;;) {
    __syncthreads();
    if (tid == 0)
      *sBC = __hip_atomic_fetch_add(TILE, 1, __ATOMIC_RELAXED, __HIP_MEMORY_SCOPE_AGENT);
    __syncthreads();
    int id = *sBC;
    if (id >= NTILES) break;
    int p = id / 3144, rem = id % 3144, nb = rem / 8, b = rem % 8;
    int m = b * 4 + p;
    int thr = 128 * (p + 1) + 1;   // FEATS t<=tEnd-1 visible at f1>=tEnd+1
    {
      const int lane = tid & 63;
      const int* fp = flags + (64 + lane) * 32;
      while (!__all(aload32(fp) >= thr)) __builtin_amdgcn_s_sleep(8);
    }
    gemm_tile(FEATS, WfcT, C, bias, PARTg, smem, m * 128, nb * 128, nb);
  }
}

// ---------------- mega kernel ----------------------------------------------
__global__ __launch_bounds__(256, 2) void k_mega(
    const unsigned short* __restrict__ U0, const float* __restrict__ Whh0,
    const float* __restrict__ Wih1, const float* __restrict__ Whh1,
    unsigned short* __restrict__ FEATS, const float* __restrict__ Wfc,
    unsigned short* __restrict__ WfcT, const float* __restrict__ bfc,
    float* __restrict__ logits, float2* __restrict__ PARTg,
    unsigned int* __restrict__ h0buf, unsigned int* __restrict__ h1buf,
    int* __restrict__ flags, int* __restrict__ cnts)
{
  __shared__ __align__(16) char smem[34816];
  const int bid = blockIdx.x;
  if (bid < 16)
    rec0_body(U0, Whh0, h0buf, flags, smem, bid);
  else if (bid < 48)
    rec1_body(Wih1, Whh1, FEATS, h0buf, h1buf, flags, smem, bid - 16);
  else
    worker_body(Wfc, WfcT, FEATS, bfc, logits, PARTg, flags,
                cnts + 0, cnts + 16, smem, bid - 48);
}

// ---------------- loss: combine per-tile partials ---------------------------
__global__ __launch_bounds__(64) void k_loss_combine(
    const float2* __restrict__ PARTg, const float* __restrict__ logits,
    const int* __restrict__ y, float* __restrict__ rowloss)
{
  const int row = blockIdx.x, l = threadIdx.x;
  float M = -1e30f, S = 0.f;
  for (int i = l; i < 393; i += 64) {
    float2 p = PARTg[(size_t)row * 393 + i];
    float nm = fmaxf(M, p.x);
    S = S * __expf(M - nm) + p.y * __expf(p.x - nm);
    M = nm;
  }
#pragma unroll
  for (int off = 32; off > 0; off >>= 1) {
    float mo = __shfl_xor(M, off), so = __shfl_xor(S, off);
    float nm = fmaxf(M, mo);
    S = S * __expf(M - nm) + so * __expf(mo - nm);
    M = nm;
  }
  if (l == 0) {
    int tgt = y[row];
    float r = 0.f;
    if (tgt >= 0) r = M + __logf(S) - logits[(size_t)row * V_SZ + tgt];
    rowloss[row] = r;
  }
}

__global__ __launch_bounds__(256) void k_loss_final(
    const float* __restrict__ rowloss, const int* __restrict__ y,
    float* __restrict__ out)
{
  const int tid = threadIdx.x;
  float s = 0.f, c = 0.f;
  for (int i = tid; i < B_SZ * T_SZ; i += 256) {
    if (y[i] != -1) { s += rowloss[i]; c += 1.f; }
  }
  for (int off = 32; off > 0; off >>= 1) { s += __shfl_xor(s, off); c += __shfl_xor(c, off); }
  __shared__ float as_[4], ac_[4];
  const int wvi = tid >> 6, lnn = tid & 63;
  if (lnn == 0) { as_[wvi] = s; ac_[wvi] = c; }
  __syncthreads();
  if (tid == 0) {
    float S = as_[0] + as_[1] + as_[2] + as_[3];
    float C = ac_[0] + ac_[1] + ac_[2] + ac_[3];
    out[0] = S / fmaxf(C, 1.f);
  }
}

// ---------------- launch ----------------------------------------------------
extern "C" void kernel_launch(void* const* d_in, const int* in_sizes, int n_in,
                              void* d_out, int out_size, void* d_ws, size_t ws_size,
                              hipStream_t stream) {
  (void)in_sizes; (void)n_in; (void)ws_size;
  const int* x = (const int*)d_in[0];
  const int* y = (const int*)d_in[1];
  const float* E = (const float*)d_in[2];
  const float* Wih0 = (const float*)d_in[3];
  const float* Whh0 = (const float*)d_in[4];
  const float* Wih1 = (const float*)d_in[5];
  const float* Whh1 = (const float*)d_in[6];
  const float* Wfc = (const float*)d_in[7];
  const float* bfc = (const float*)d_in[8];
  char* ws = (char*)d_ws;
  // workspace layout (bytes)
  unsigned short* WfcT  = (unsigned short*)(ws + 0ULL);            // 103,022,592
  unsigned short* Wih0T = (unsigned short*)(ws + 103022592ULL);    // 1,048,576
  unsigned short* XE    = (unsigned short*)(ws + 104071168ULL);    // 4,194,304
  unsigned short* U0    = (unsigned short*)(ws + 108265472ULL);    // 8,388,608
  unsigned short* FEATS = (unsigned short*)(ws + 116654080ULL);    // 8,388,608
  float2* PART          = (float2*)(ws + 125042688ULL);            // 12,877,824
  float* ROWLOSS        = (float*)(ws + 137920512ULL);             // 16,384
  unsigned int* H0u     = (unsigned int*)(ws + 137936896ULL);      // 32,768
  unsigned int* H1u     = (unsigned int*)(ws + 137969664ULL);      // 32,768
  int* FLAGS            = (int*)(ws + 138002432ULL);               // 16,384
  int* CNT              = (int*)(ws + 138018816ULL);               // 256
  float* logits = (float*)d_out;
  float* lossp = logits + (size_t)(out_size - 1);

  // zero h ping-pong buffers + flags + counters (fresh every replay)
  hipMemsetAsync(ws + 137936896ULL, 0, 82176, stream);

  // pre: Wih0 transpose, embed, U0 GEMM
  k_transpose<<<dim3(32, 16), dim3(32, 8), 0, stream>>>(Wih0, Wih0T, 512, 1024, 1024);
  k_embed<<<4096, 128, 0, stream>>>(x, E, XE);
  k_gemm<true, false><<<dim3(8, 32), 256, 0, stream>>>(XE, Wih0T, U0, nullptr,
                                                       1024, 512, 512, 512, 1024);
  // mega: fused rec L0+L1 + Wfc transpose + gated logits GEMM + lse partials
  k_mega<<<512, 256, 0, stream>>>(U0, Whh0, Wih1, Whh1, FEATS, Wfc, WfcT, bfc,
                                  logits, PART, H0u, H1u, FLAGS, CNT);
  // loss
  k_loss_combine<<<4096, 64, 0, stream>>>(PART, logits, y, ROWLOSS);
  k_loss_final<<<1, 256, 0, stream>>>(ROWLOSS, y, lossp);
}

// Round 5
// 3304.123 us; speedup vs baseline: 1.5175x; 1.5175x over previous
//
#include <hip/hip_runtime.h>

// ---------------------------------------------------------------------------
// 2-layer Elman RNN LM forward on MI355X — tag-in-data recurrence edition.
// Pre: Wih0/Wfc transposes, embed, U0 GEMM.
// k_rectag (96 WGs x 128 thr): fence-free, ack-free, flag-free recurrence.
//   Every h value travels as an 8B slot {tag=t+1, payload=2xbf16} in a
//   4-deep ring; writers fire-and-forget one atomic 8B store per slot;
//   readers' gather loop IS the poll (re-issue until all tags match).
//   WGs 0-31: layer0 (2 independent waves, 16 cols each, Whh0 in VGPRs,
//   zero barriers). WGs 32-95: layer1 (wave A: h0@Wih1, wave B: h1@Whh1 +
//   combine + output; one 2-wave barrier/tick). Lazy backpressure via a
//   fire-and-forget progress flag checked 4 ticks deep.
// Then: logits GEMM with fused per-tile logsumexp partials -> combine -> loss.
// ---------------------------------------------------------------------------

#define H_DIM 1024
#define B_SZ 8
#define T_SZ 512
#define V_SZ 50257
#define V_PAD 50304

typedef __attribute__((ext_vector_type(8))) short bf16x8;
typedef __attribute__((ext_vector_type(4))) float f32x4;

__device__ __forceinline__ unsigned short f2bf(float f) {
  unsigned int u = __float_as_uint(f);
  u += 0x7fffu + ((u >> 16) & 1u);   // round-to-nearest-even
  return (unsigned short)(u >> 16);
}
__device__ __forceinline__ float bf2f(unsigned short h) {
  return __uint_as_float(((unsigned int)h) << 16);
}
__device__ __forceinline__ float ftanh(float x) {
  float e = __expf(2.f * x);
  return 1.f - 2.f / (e + 1.f);
}
__device__ __forceinline__ int aload32(const int* p) {
  return __hip_atomic_load(p, __ATOMIC_RELAXED, __HIP_MEMORY_SCOPE_AGENT);
}
__device__ __forceinline__ void astore32i(int* p, int v) {
  __hip_atomic_store(p, v, __ATOMIC_RELAXED, __HIP_MEMORY_SCOPE_AGENT);
}
__device__ __forceinline__ unsigned long long aload64(const void* p) {
  return __hip_atomic_load((const unsigned long long*)p, __ATOMIC_RELAXED,
                           __HIP_MEMORY_SCOPE_AGENT);
}
__device__ __forceinline__ void astore64(void* p, unsigned long long v) {
  __hip_atomic_store((unsigned long long*)p, v, __ATOMIC_RELAXED,
                     __HIP_MEMORY_SCOPE_AGENT);
}
__device__ __forceinline__ void gload_lds16(const void* g, void* l) {
  __builtin_amdgcn_global_load_lds(
      (const __attribute__((address_space(1))) void*)g,
      (__attribute__((address_space(3))) void*)l, 16, 0, 0);
}

// ---------------- transpose f32 [K][N] -> bf16 [Npad][K] --------------------
__global__ __launch_bounds__(256) void k_transpose(
    const float* __restrict__ in, unsigned short* __restrict__ out,
    int K, int N, int Npad)
{
  __shared__ float tile[32][33];
  const int n0 = blockIdx.x * 32, k0 = blockIdx.y * 32;
  const int tx = threadIdx.x, ty = threadIdx.y;
#pragma unroll
  for (int jj = 0; jj < 4; ++jj) {
    int k = k0 + ty + jj * 8, n = n0 + tx;
    tile[ty + jj * 8][tx] = (n < N) ? in[(size_t)k * N + n] : 0.f;
  }
  __syncthreads();
#pragma unroll
  for (int jj = 0; jj < 4; ++jj) {
    int n = n0 + ty + jj * 8, k = k0 + tx;
    if (n < Npad) out[(size_t)n * K + k] = f2bf((n < N) ? tile[tx][ty + jj * 8] : 0.f);
  }
}

// ---------------- embedding gather -> time-major bf16 [T*B][512] ------------
__global__ __launch_bounds__(128) void k_embed(
    const int* __restrict__ x, const float* __restrict__ E,
    unsigned short* __restrict__ xe)
{
  const int r = blockIdx.x;            // time-major row t*8+b
  const int t = r >> 3, b = r & 7;
  const int tok = x[b * T_SZ + t];
  const float4 v = ((const float4*)(E + (size_t)tok * 512))[threadIdx.x];
  ushort4 o;
  o.x = f2bf(v.x); o.y = f2bf(v.y); o.z = f2bf(v.z); o.w = f2bf(v.w);
  *((ushort4*)(xe + (size_t)r * 512) + threadIdx.x) = o;
}

// ---------------- bf16 MFMA GEMM (U0): C = A @ Bt^T -------------------------
template <bool BF16_OUT, bool BIAS>
__global__ __launch_bounds__(256) void k_gemm(
    const unsigned short* __restrict__ A, const unsigned short* __restrict__ Bt,
    void* __restrict__ Cout, const float* __restrict__ bias,
    int Nvalid, int K, int lda, int ldb, int ldc)
{
  __shared__ unsigned short As[8192];
  __shared__ unsigned short Bs[8192];
  const int tid = threadIdx.x;
  const int n0 = blockIdx.x * 128;
  const int m0 = blockIdx.y * 128;
  const int lane = tid & 63;
  const int wv = tid >> 6;
  const int wm = wv >> 1, wn = wv & 1;
  const int ln = lane & 15, cc = lane >> 4;
  f32x4 acc[4][4] = {};
  const int rr = tid >> 3;
  const int cb = (tid & 7) << 4;

  for (int kb = 0; kb < K; kb += 64) {
    __syncthreads();
#pragma unroll
    for (int is = 0; is < 4; ++is) {
      int r = is * 32 + rr;
      int sb = cb ^ ((r & 7) << 4);
      gload_lds16((const char*)(A + (size_t)(m0 + r) * lda + kb) + sb,
                  &As[(is * 32 + 8 * wv) * 64]);
    }
#pragma unroll
    for (int is = 0; is < 4; ++is) {
      int r = is * 32 + rr;
      int sb = cb ^ ((r & 7) << 4);
      gload_lds16((const char*)(Bt + (size_t)(n0 + r) * ldb + kb) + sb,
                  &Bs[(is * 32 + 8 * wv) * 64]);
    }
    __syncthreads();
#pragma unroll
    for (int kk = 0; kk < 2; ++kk) {
      bf16x8 af[4], bfr[4];
      const int kslot = kk * 64 + cc * 16;
#pragma unroll
      for (int mi = 0; mi < 4; ++mi) {
        int ra = wm * 64 + mi * 16 + ln;
        af[mi] = *(const bf16x8*)((const char*)As + ra * 128 + (kslot ^ ((ra & 7) << 4)));
      }
#pragma unroll
      for (int ni = 0; ni < 4; ++ni) {
        int rb = wn * 64 + ni * 16 + ln;
        bfr[ni] = *(const bf16x8*)((const char*)Bs + rb * 128 + (kslot ^ ((rb & 7) << 4)));
      }
#pragma unroll
      for (int mi = 0; mi < 4; ++mi)
#pragma unroll
        for (int ni = 0; ni < 4; ++ni)
          acc[mi][ni] = __builtin_amdgcn_mfma_f32_16x16x32_bf16(af[mi], bfr[ni], acc[mi][ni], 0, 0, 0);
    }
  }
#pragma unroll
  for (int ni = 0; ni < 4; ++ni) {
    const int col = n0 + wn * 64 + ni * 16 + ln;
    const bool cok = col < Nvalid;
    float bv = 0.f;
    if (BIAS && cok) bv = bias[col];
#pragma unroll
    for (int mi = 0; mi < 4; ++mi) {
#pragma unroll
      for (int i = 0; i < 4; ++i) {
        if (cok) {
          const int rowg = m0 + wm * 64 + mi * 16 + cc * 4 + i;
          if (BF16_OUT)
            ((unsigned short*)Cout)[(size_t)rowg * ldc + col] = f2bf(acc[mi][ni][i]);
          else
            ((float*)Cout)[(size_t)rowg * ldc + col] = acc[mi][ni][i] + bv;
        }
      }
    }
  }
}

// ---------------- tag-in-data recurrence ------------------------------------
// slot s = row*512 + kpair (row=batch 0..7, kpair=0..511). 8B = {tag, 2xbf16}.
// ring[t&3] holds h[t], tagged t+1; memset(0) == h[-1..-4] tagged 0.

// gather 4096 slots of one ring slot-page into wave-private swizzled LDS;
// lane handles slots q*64+lane (coalesced). Re-issues until all tags == want.
__device__ __forceinline__ void gather_stage(const uint2* __restrict__ sl,
    unsigned want, char* __restrict__ lds, int lane)
{
  unsigned pay[64];
  for (;;) {
    unsigned long long v[64];
#pragma unroll
    for (int q = 0; q < 64; ++q)
      v[q] = aload64(sl + q * 64 + lane);
    bool ok = true;
#pragma unroll
    for (int q = 0; q < 64; ++q) {
      ok &= ((unsigned)v[q] == want);
      pay[q] = (unsigned)(v[q] >> 32);
    }
    if (__all(ok)) break;
  }
#pragma unroll
  for (int q = 0; q < 64; ++q) {
    int s = q * 64 + lane;
    int row = s >> 9, kp = s & 511;
    *(unsigned*)(lds + ((row * 2048 + kp * 4) ^ ((row & 7) << 4))) = pay[q];
  }
}

__device__ __forceinline__ void load_bw(bf16x8* bw, const float* W, int cc, int col)
{
#pragma unroll
  for (int kc = 0; kc < 32; ++kc) {
    const float* wp = W + (size_t)(kc * 32 + cc * 8) * H_DIM + col;
    bf16x8 v;
#pragma unroll
    for (int q = 0; q < 8; ++q) v[q] = (short)f2bf(wp[(size_t)q * H_DIM]);
    bw[kc] = v;
  }
}

__device__ __forceinline__ f32x4 mfma_k1024(const char* hs, const bf16x8* bw,
                                            int cc, int r)
{
  f32x4 ac0 = {}, ac1 = {};
  const int swz = r << 4;
#pragma unroll
  for (int kc = 0; kc < 32; kc += 2) {
    bf16x8 a0 = *(const bf16x8*)(hs + r * 2048 + ((kc * 64 + cc * 16) ^ swz));
    bf16x8 a1 = *(const bf16x8*)(hs + r * 2048 + (((kc + 1) * 64 + cc * 16) ^ swz));
    ac0 = __builtin_amdgcn_mfma_f32_16x16x32_bf16(a0, bw[kc], ac0, 0, 0, 0);
    ac1 = __builtin_amdgcn_mfma_f32_16x16x32_bf16(a1, bw[kc + 1], ac1, 0, 0, 0);
  }
  return ac0 + ac1;
}

// layer 0: one independent wave per 16-col tile, zero barriers.
__device__ void rec0w(const unsigned short* U0, const float* Whh0,
    uint2* h0ring, const int* prog, char* myl, int w)
{
  const int lane = threadIdx.x & 63;
  const int ln = lane & 15, cc = lane >> 4, r = ln & 7;
  const int col = w * 16 + ln;
  bf16x8 bw[32];
  load_bw(bw, Whh0, cc, col);
#pragma unroll 1
  for (int t = 0; t < T_SZ; ++t) {
    unsigned short uva[4] = {0, 0, 0, 0};
    if (cc < 2) {
#pragma unroll
      for (int i = 0; i < 4; ++i)
        uva[i] = U0[(size_t)(t * B_SZ + cc * 4 + i) * H_DIM + col];
    }
    // gather h0[t-1] (tag t); the gather IS the poll
    gather_stage(h0ring + ((t + 3) & 3) * 4096, (unsigned)t, myl, lane);
    f32x4 ac = mfma_k1024(myl, bw, cc, r);
    float hv[4] = {0.f, 0.f, 0.f, 0.f};
    if (cc < 2) {
#pragma unroll
      for (int i = 0; i < 4; ++i) hv[i] = ftanh(ac[i] + bf2f(uva[i]));
    }
    unsigned wpk[4];
#pragma unroll
    for (int i = 0; i < 4; ++i) {
      float pv = __shfl_xor(hv[i], 1);
      wpk[i] = (unsigned)f2bf(hv[i]) | ((unsigned)f2bf(pv) << 16);
    }
    // backpressure: h0[t] overwrites h0[t-4]; L1 (consumer) must be >= t-3.
    if (t >= 4) {
      const int* pp = prog + lane;
      while (!__all(aload32(pp) >= t - 3)) __builtin_amdgcn_s_sleep(1);
    }
    if (cc < 2 && !(ln & 1)) {
      uint2* outs = h0ring + (t & 3) * 4096;
      const int kp = w * 8 + (ln >> 1);
#pragma unroll
      for (int i = 0; i < 4; ++i)
        astore64(outs + (cc * 4 + i) * 512 + kp,
                 ((unsigned long long)wpk[i] << 32) | (unsigned long long)(t + 1));
    }
  }
}

// layer 1: wave A = h0[t]@Wih1 partial, wave B = h1[t-1]@Whh1 + combine + out.
__device__ void rec1w(const float* Wih1, const float* Whh1,
    unsigned short* feats, uint2* h0ring, uint2* h1ring, int* prog,
    char* smem, int w)
{
  const int tid = threadIdx.x;
  const int lane = tid & 63, wv = tid >> 6;
  const int ln = lane & 15, cc = lane >> 4, r = ln & 7;
  const int col = w * 16 + ln;
  float* part = (float*)(smem + 32768);   // 2 x 1KB, parity double-buffered
  if (wv == 0) {
    char* myl = smem;
    bf16x8 bw[32];
    load_bw(bw, Wih1, cc, col);
#pragma unroll 1
    for (int t = 0; t < T_SZ; ++t) {
      gather_stage(h0ring + (t & 3) * 4096, (unsigned)(t + 1), myl, lane);
      f32x4 ac = mfma_k1024(myl, bw, cc, r);
      *(f32x4*)(part + (t & 1) * 256 + lane * 4) = ac;
      __syncthreads();
    }
  } else {
    char* myl = smem + 16384;
    bf16x8 bw[32];
    load_bw(bw, Whh1, cc, col);
#pragma unroll 1
    for (int t = 0; t < T_SZ; ++t) {
      gather_stage(h1ring + ((t + 3) & 3) * 4096, (unsigned)t, myl, lane);
      f32x4 ac = mfma_k1024(myl, bw, cc, r);
      __syncthreads();                    // A's partial for tick t is ready
      f32x4 pa = *(const f32x4*)(part + (t & 1) * 256 + lane * 4);
      float hv[4] = {0.f, 0.f, 0.f, 0.f};
      if (cc < 2) {
#pragma unroll
        for (int i = 0; i < 4; ++i) hv[i] = ftanh(ac[i] + pa[i]);
      }
      unsigned wpk[4];
#pragma unroll
      for (int i = 0; i < 4; ++i) {
        float pv = __shfl_xor(hv[i], 1);
        wpk[i] = (unsigned)f2bf(hv[i]) | ((unsigned)f2bf(pv) << 16);
      }
      if (cc < 2 && !(ln & 1)) {
        uint2* outs = h1ring + (t & 3) * 4096;
        const int kp = w * 8 + (ln >> 1);
#pragma unroll
        for (int i = 0; i < 4; ++i) {
          astore64(outs + (cc * 4 + i) * 512 + kp,
                   ((unsigned long long)wpk[i] << 32) | (unsigned long long)(t + 1));
          *(unsigned*)(feats + (size_t)(cc * 4 + i) * 524288 +
                       (size_t)t * 1024 + col) = wpk[i];
        }
      }
      if (lane == 0) astore32i(prog + w, t + 1);  // fire-and-forget progress
    }
  }
}

__global__ __launch_bounds__(128, 1) void k_rectag(
    const unsigned short* __restrict__ U0,
    const float* __restrict__ Whh0, const float* __restrict__ Wih1,
    const float* __restrict__ Whh1, unsigned short* __restrict__ FEATS,
    uint2* __restrict__ h0ring, uint2* __restrict__ h1ring,
    int* __restrict__ prog)
{
  __shared__ __align__(16) char smem[34816];
  const int bid = blockIdx.x;
  const int wv = threadIdx.x >> 6;
  if (bid < 32)
    rec0w(U0, Whh0, h0ring, prog, smem + wv * 16384, bid * 2 + wv);
  else
    rec1w(Wih1, Whh1, FEATS, h0ring, h1ring, prog, smem, bid - 32);
}

// ---------------- logits GEMM + fused per-tile logsumexp partials -----------
__global__ __launch_bounds__(256) void k_gemm_lse(
    const unsigned short* __restrict__ A, const unsigned short* __restrict__ Bt,
    float* __restrict__ C, const float* __restrict__ bias,
    float2* __restrict__ PARTg)
{
  __shared__ __align__(16) char smem[33792];
  unsigned short* As = (unsigned short*)smem;
  unsigned short* Bs = (unsigned short*)(smem + 16384);
  float2* lpart = (float2*)(smem + 32768);
  const int nb = blockIdx.x;
  const int m0 = blockIdx.y * 128, n0 = nb * 128;
  const int tid = threadIdx.x;
  const int lane = tid & 63;
  const int wv = tid >> 6;
  const int wm = wv >> 1, wn = wv & 1;
  const int ln = lane & 15, cc = lane >> 4;
  f32x4 acc[4][4] = {};
  const int rr = tid >> 3;
  const int cb = (tid & 7) << 4;

  for (int kb = 0; kb < H_DIM; kb += 64) {
    __syncthreads();
#pragma unroll
    for (int is = 0; is < 4; ++is) {
      int r = is * 32 + rr;
      int sb = cb ^ ((r & 7) << 4);
      gload_lds16((const char*)(A + (size_t)(m0 + r) * H_DIM + kb) + sb,
                  &As[(is * 32 + 8 * wv) * 64]);
    }
#pragma unroll
    for (int is = 0; is < 4; ++is) {
      int r = is * 32 + rr;
      int sb = cb ^ ((r & 7) << 4);
      gload_lds16((const char*)(Bt + (size_t)(n0 + r) * H_DIM + kb) + sb,
                  &Bs[(is * 32 + 8 * wv) * 64]);
    }
    __syncthreads();
#pragma unroll
    for (int kk = 0; kk < 2; ++kk) {
      bf16x8 af[4], bfr[4];
      const int kslot = kk * 64 + cc * 16;
#pragma unroll
      for (int mi = 0; mi < 4; ++mi) {
        int ra = wm * 64 + mi * 16 + ln;
        af[mi] = *(const bf16x8*)((const char*)As + ra * 128 + (kslot ^ ((ra & 7) << 4)));
      }
#pragma unroll
      for (int ni = 0; ni < 4; ++ni) {
        int rb = wn * 64 + ni * 16 + ln;
        bfr[ni] = *(const bf16x8*)((const char*)Bs + rb * 128 + (kslot ^ ((rb & 7) << 4)));
      }
#pragma unroll
      for (int mi = 0; mi < 4; ++mi)
#pragma unroll
        for (int ni = 0; ni < 4; ++ni)
          acc[mi][ni] = __builtin_amdgcn_mfma_f32_16x16x32_bf16(af[mi], bfr[ni], acc[mi][ni], 0, 0, 0);
    }
  }
  float bvn[4]; int ckn[4];
#pragma unroll
  for (int ni = 0; ni < 4; ++ni) {
    int col = n0 + wn * 64 + ni * 16 + ln;
    ckn[ni] = col < V_SZ;
    bvn[ni] = ckn[ni] ? bias[col] : 0.f;
  }
  float fm[16], fs[16];
#pragma unroll
  for (int mi = 0; mi < 4; ++mi) {
#pragma unroll
    for (int i = 0; i < 4; ++i) {
      float v[4];
#pragma unroll
      for (int ni = 0; ni < 4; ++ni) {
        float tv = acc[mi][ni][i] + bvn[ni];
        v[ni] = ckn[ni] ? tv : -1e30f;
        if (ckn[ni]) {
          int col = n0 + wn * 64 + ni * 16 + ln;
          C[(size_t)(m0 + wm * 64 + mi * 16 + cc * 4 + i) * V_SZ + col] = tv;
        }
      }
      float mx = fmaxf(fmaxf(v[0], v[1]), fmaxf(v[2], v[3]));
#pragma unroll
      for (int m = 1; m < 16; m <<= 1) mx = fmaxf(mx, __shfl_xor(mx, m));
      float se = __expf(v[0] - mx) + __expf(v[1] - mx) +
                 __expf(v[2] - mx) + __expf(v[3] - mx);
#pragma unroll
      for (int m = 1; m < 16; m <<= 1) se += __shfl_xor(se, m);
      fm[mi * 4 + i] = mx; fs[mi * 4 + i] = se;
    }
  }
  if (wn == 0 && ln == 0) {
#pragma unroll
    for (int mi = 0; mi < 4; ++mi)
#pragma unroll
      for (int i = 0; i < 4; ++i) {
        int rl = wm * 64 + mi * 16 + cc * 4 + i;
        lpart[rl] = make_float2(fm[mi * 4 + i], fs[mi * 4 + i]);
      }
  }
  __syncthreads();
  if (wn == 1 && ln == 0) {
#pragma unroll
    for (int mi = 0; mi < 4; ++mi)
#pragma unroll
      for (int i = 0; i < 4; ++i) {
        int rl = wm * 64 + mi * 16 + cc * 4 + i;
        float2 o = lpart[rl];
        float mx = fm[mi * 4 + i], se = fs[mi * 4 + i];
        float nm = fmaxf(mx, o.x);
        float S = se * __expf(mx - nm) + o.y * __expf(o.x - nm);
        PARTg[(size_t)(m0 + rl) * 393 + nb] = make_float2(nm, S);
      }
  }
}

// ---------------- loss: combine per-tile partials ---------------------------
__global__ __launch_bounds__(64) void k_loss_combine(
    const float2* __restrict__ PARTg, const float* __restrict__ logits,
    const int* __restrict__ y, float* __restrict__ rowloss)
{
  const int row = blockIdx.x, l = threadIdx.x;
  float M = -1e30f, S = 0.f;
  for (int i = l; i < 393; i += 64) {
    float2 p = PARTg[(size_t)row * 393 + i];
    float nm = fmaxf(M, p.x);
    S = S * __expf(M - nm) + p.y * __expf(p.x - nm);
    M = nm;
  }
#pragma unroll
  for (int off = 32; off > 0; off >>= 1) {
    float mo = __shfl_xor(M, off), so = __shfl_xor(S, off);
    float nm = fmaxf(M, mo);
    S = S * __expf(M - nm) + so * __expf(mo - nm);
    M = nm;
  }
  if (l == 0) {
    int tgt = y[row];
    float r = 0.f;
    if (tgt >= 0) r = M + __logf(S) - logits[(size_t)row * V_SZ + tgt];
    rowloss[row] = r;
  }
}

__global__ __launch_bounds__(256) void k_loss_final(
    const float* __restrict__ rowloss, const int* __restrict__ y,
    float* __restrict__ out)
{
  const int tid = threadIdx.x;
  float s = 0.f, c = 0.f;
  for (int i = tid; i < B_SZ * T_SZ; i += 256) {
    if (y[i] != -1) { s += rowloss[i]; c += 1.f; }
  }
  for (int off = 32; off > 0; off >>= 1) { s += __shfl_xor(s, off); c += __shfl_xor(c, off); }
  __shared__ float as_[4], ac_[4];
  const int wvi = tid >> 6, lnn = tid & 63;
  if (lnn == 0) { as_[wvi] = s; ac_[wvi] = c; }
  __syncthreads();
  if (tid == 0) {
    float S = as_[0] + as_[1] + as_[2] + as_[3];
    float C = ac_[0] + ac_[1] + ac_[2] + ac_[3];
    out[0] = S / fmaxf(C, 1.f);
  }
}

// ---------------- launch ----------------------------------------------------
extern "C" void kernel_launch(void* const* d_in, const int* in_sizes, int n_in,
                              void* d_out, int out_size, void* d_ws, size_t ws_size,
                              hipStream_t stream) {
  (void)in_sizes; (void)n_in; (void)ws_size;
  const int* x = (const int*)d_in[0];
  const int* y = (const int*)d_in[1];
  const float* E = (const float*)d_in[2];
  const float* Wih0 = (const float*)d_in[3];
  const float* Whh0 = (const float*)d_in[4];
  const float* Wih1 = (const float*)d_in[5];
  const float* Whh1 = (const float*)d_in[6];
  const float* Wfc = (const float*)d_in[7];
  const float* bfc = (const float*)d_in[8];
  char* ws = (char*)d_ws;
  // workspace layout (bytes)
  unsigned short* WfcT  = (unsigned short*)(ws + 0ULL);            // 103,022,592
  unsigned short* Wih0T = (unsigned short*)(ws + 103022592ULL);    // 1,048,576
  unsigned short* XE    = (unsigned short*)(ws + 104071168ULL);    // 4,194,304
  unsigned short* U0    = (unsigned short*)(ws + 108265472ULL);    // 8,388,608
  unsigned short* FEATS = (unsigned short*)(ws + 116654080ULL);    // 8,388,608
  float2* PART          = (float2*)(ws + 125042688ULL);            // 12,877,824
  float* ROWLOSS        = (float*)(ws + 137920512ULL);             // 16,384
  uint2* H0R            = (uint2*)(ws + 137936896ULL);             // 131,072
  uint2* H1R            = (uint2*)(ws + 138067968ULL);             // 131,072
  int* PROG             = (int*)(ws + 138199040ULL);               // 256
  float* logits = (float*)d_out;
  float* lossp = logits + (size_t)(out_size - 1);

  // zero h rings (tags = 0 == "h[-1] ready") + progress flags, every replay
  hipMemsetAsync(ws + 137936896ULL, 0, 262400, stream);

  // pre: weight transposes, embed, U0 GEMM
  k_transpose<<<dim3(32, 16), dim3(32, 8), 0, stream>>>(Wih0, Wih0T, 512, 1024, 1024);
  k_transpose<<<dim3(1572, 32), dim3(32, 8), 0, stream>>>(Wfc, WfcT, 1024, V_SZ, V_PAD);
  k_embed<<<4096, 128, 0, stream>>>(x, E, XE);
  k_gemm<true, false><<<dim3(8, 32), 256, 0, stream>>>(XE, Wih0T, U0, nullptr,
                                                       1024, 512, 512, 512, 1024);
  // fused 2-layer recurrence, tag-in-data protocol
  k_rectag<<<96, 128, 0, stream>>>(U0, Whh0, Wih1, Whh1, FEATS, H0R, H1R, PROG);
  // logits GEMM + lse partials
  k_gemm_lse<<<dim3(393, 32), 256, 0, stream>>>(FEATS, WfcT, logits, bfc, PART);
  // loss
  k_loss_combine<<<4096, 64, 0, stream>>>(PART, logits, y, ROWLOSS);
  k_loss_final<<<1, 256, 0, stream>>>(ROWLOSS, y, lossp);
}